// Round 2
// baseline (3292.270 us; speedup 1.0000x reference)
//
#include <hip/hip_runtime.h>
#include <hip/hip_bf16.h>
#include <cfloat>

// GATv2 layer pipeline:
//   1) proj_gemm: fs = X@Wsrc+bsrc, fd = X@Wdst+bdst   (f32 tiled GEMM)
//   2) edge_logits: logit[e,h] = sum_d leakyrelu(fs[src]+fd[dst]) * attn_w ; atomicMax per dst
//   3) edge_exp: ex = exp(logit - m[dst]); atomicAdd s[dst]
//   4) edge_aggr: a = ex/s[dst] -> attention output; atomicAdd rst[dst] += fs[src]*a
//   5) colstats + finalize_stats + bn_relu: BatchNorm(train stats) + ReLU
//
// rst accumulates directly in d_out[0 : N*256]; attention goes to d_out[N*256 :].

#define N_NODES 50000
#define N_EDGES 800000
#define NFEAT 256
#define HEADS 4
#define HDIM 64
#define NEG_SLOPE 0.2f
#define BN_EPS 1e-5f

// ---- monotonic float<->uint transform for atomicMax on floats ----
__device__ __forceinline__ unsigned f2mono(float f) {
    unsigned u = __float_as_uint(f);
    return (u & 0x80000000u) ? ~u : (u | 0x80000000u);
}
__device__ __forceinline__ float mono2f(unsigned v) {
    unsigned u = (v & 0x80000000u) ? (v ^ 0x80000000u) : ~v;
    return __uint_as_float(u);
}

// ---------------- 1) projection GEMM (f32) ----------------
// C tile BM=128 x BN=64, BK=16, 256 threads, 8x4 per thread.
#define BM 128
#define BN 64
#define BK 16

__global__ __launch_bounds__(256) void proj_gemm(
    const float* __restrict__ X,
    const float* __restrict__ Wsrc, const float* __restrict__ bsrc,
    const float* __restrict__ Wdst, const float* __restrict__ bdst,
    float* __restrict__ fs, float* __restrict__ fd)
{
    const int bm = blockIdx.x;
    const int bn = blockIdx.y;     // 0..7 : 0-3 -> fs, 4-7 -> fd
    const float* W;  const float* bvec;  float* out;  int ncol0;
    if (bn < 4) { W = Wsrc; bvec = bsrc; out = fs; ncol0 = bn * 64; }
    else        { W = Wdst; bvec = bdst; out = fd; ncol0 = (bn - 4) * 64; }

    __shared__ float As[BK][BM + 4];
    __shared__ float Bs[BK][BN];

    const int tid = threadIdx.x;
    const int tm = (tid >> 4) * 8;   // 0..120
    const int tn = (tid & 15) * 4;   // 0..60
    const int row0 = bm * BM;

    float acc[8][4] = {};

    for (int k0 = 0; k0 < NFEAT; k0 += BK) {
        // A tile: 128 rows x 16 k, float4 along k, transposed store to LDS
        #pragma unroll
        for (int i = 0; i < 2; i++) {
            int idx = tid + i * 256;           // 0..511
            int r = idx >> 2;                  // 0..127
            int kq = (idx & 3) * 4;            // 0,4,8,12
            float4 v = make_float4(0.f, 0.f, 0.f, 0.f);
            int gr = row0 + r;
            if (gr < N_NODES)
                v = *(const float4*)&X[(size_t)gr * NFEAT + k0 + kq];
            As[kq + 0][r] = v.x; As[kq + 1][r] = v.y;
            As[kq + 2][r] = v.z; As[kq + 3][r] = v.w;
        }
        // B tile: 16 k x 64 n, direct
        {
            int kr = tid >> 4;                 // 0..15
            int nq = (tid & 15) * 4;           // 0..60
            float4 v = *(const float4*)&W[(size_t)(k0 + kr) * (HEADS * HDIM) + ncol0 + nq];
            *(float4*)&Bs[kr][nq] = v;
        }
        __syncthreads();

        #pragma unroll
        for (int kk = 0; kk < BK; kk++) {
            float a0[8];
            #pragma unroll
            for (int i = 0; i < 8; i++) a0[i] = As[kk][tm + i];
            float4 b4 = *(float4*)&Bs[kk][tn];
            float b[4] = { b4.x, b4.y, b4.z, b4.w };
            #pragma unroll
            for (int i = 0; i < 8; i++)
                #pragma unroll
                for (int j = 0; j < 4; j++)
                    acc[i][j] += a0[i] * b[j];
        }
        __syncthreads();
    }

    float4 bb = *(const float4*)&bvec[ncol0 + tn];
    #pragma unroll
    for (int i = 0; i < 8; i++) {
        int gr = row0 + tm + i;
        if (gr < N_NODES) {
            float4 v;
            v.x = acc[i][0] + bb.x;
            v.y = acc[i][1] + bb.y;
            v.z = acc[i][2] + bb.z;
            v.w = acc[i][3] + bb.w;
            *(float4*)&out[(size_t)gr * NFEAT + ncol0 + tn] = v;
        }
    }
}

// ---------------- 2) edge logits + segment max ----------------
// one wave (64 lanes) per edge; lane handles dims 4*lane..4*lane+3
__global__ __launch_bounds__(256) void edge_logits(
    const float* __restrict__ fs, const float* __restrict__ fd,
    const int* __restrict__ src, const int* __restrict__ dst,
    const float* __restrict__ attn_w,
    float* __restrict__ logits, unsigned* __restrict__ m_u)
{
    int e = blockIdx.x * 4 + (threadIdx.x >> 6);
    if (e >= N_EDGES) return;
    int lane = threadIdx.x & 63;
    int si = src[e], di = dst[e];
    float4 u = *(const float4*)&fs[(size_t)si * NFEAT + lane * 4];
    float4 v = *(const float4*)&fd[(size_t)di * NFEAT + lane * 4];
    float4 w = *(const float4*)&attn_w[lane * 4];
    float p = 0.f, x;
    x = u.x + v.x; x = x > 0.f ? x : NEG_SLOPE * x; p += x * w.x;
    x = u.y + v.y; x = x > 0.f ? x : NEG_SLOPE * x; p += x * w.y;
    x = u.z + v.z; x = x > 0.f ? x : NEG_SLOPE * x; p += x * w.z;
    x = u.w + v.w; x = x > 0.f ? x : NEG_SLOPE * x; p += x * w.w;
    // reduce over 16-lane head group
    #pragma unroll
    for (int off = 8; off; off >>= 1) p += __shfl_xor(p, off, 16);
    if ((lane & 15) == 0) {
        int h = lane >> 4;
        logits[(size_t)e * HEADS + h] = p;
        atomicMax(&m_u[(size_t)di * HEADS + h], f2mono(p));
    }
}

// ---------------- 3) exp + segment sum ----------------
__global__ __launch_bounds__(256) void edge_exp(
    const int* __restrict__ dst, float* __restrict__ logits,
    const unsigned* __restrict__ m_u, float* __restrict__ ssum)
{
    int idx = blockIdx.x * 256 + threadIdx.x;
    if (idx >= N_EDGES * HEADS) return;
    int e = idx >> 2, h = idx & 3;
    int di = dst[e];
    float mm = mono2f(m_u[(size_t)di * HEADS + h]);
    float ex = __expf(logits[idx] - mm);
    logits[idx] = ex;
    atomicAdd(&ssum[(size_t)di * HEADS + h], ex);
}

// ---------------- 4) normalize + weighted scatter-add ----------------
__global__ __launch_bounds__(256) void edge_aggr(
    const float* __restrict__ fs,
    const int* __restrict__ src, const int* __restrict__ dst,
    const float* __restrict__ ex, const float* __restrict__ ssum,
    float* __restrict__ attn_out, float* __restrict__ rst)
{
    int e = blockIdx.x * 4 + (threadIdx.x >> 6);
    if (e >= N_EDGES) return;
    int lane = threadIdx.x & 63;
    int si = src[e], di = dst[e];
    int h = lane >> 4;
    float a = ex[(size_t)e * HEADS + h] / ssum[(size_t)di * HEADS + h];
    if ((lane & 15) == 0) attn_out[(size_t)e * HEADS + h] = a;
    float4 u = *(const float4*)&fs[(size_t)si * NFEAT + lane * 4];
    float* base = &rst[(size_t)di * NFEAT + lane * 4];
    atomicAdd(base + 0, u.x * a);
    atomicAdd(base + 1, u.y * a);
    atomicAdd(base + 2, u.z * a);
    atomicAdd(base + 3, u.w * a);
}

// ---------------- 5) BatchNorm stats ----------------
__global__ __launch_bounds__(256) void colstats(
    const float* __restrict__ rst, const float* __restrict__ X,
    const float* __restrict__ bias,
    float* __restrict__ csum, float* __restrict__ csumsq)
{
    int c = threadIdx.x;
    float b = bias[c];
    float s0 = 0.f, s1 = 0.f;
    for (int r = blockIdx.x; r < N_NODES; r += gridDim.x) {
        float v = rst[(size_t)r * NFEAT + c] + X[(size_t)r * NFEAT + c] + b;
        s0 += v; s1 += v * v;
    }
    atomicAdd(&csum[c], s0);
    atomicAdd(&csumsq[c], s1);
}

__global__ void finalize_stats(
    const float* __restrict__ csum, const float* __restrict__ csumsq,
    const float* __restrict__ gamma, const float* __restrict__ beta,
    float* __restrict__ scale, float* __restrict__ shift)
{
    int c = threadIdx.x;
    float mean = csum[c] * (1.0f / N_NODES);
    float var = csumsq[c] * (1.0f / N_NODES) - mean * mean;
    float sc = gamma[c] * rsqrtf(var + BN_EPS);
    scale[c] = sc;
    shift[c] = beta[c] - mean * sc;
}

__global__ __launch_bounds__(256) void bn_relu(
    float* __restrict__ outf, const float* __restrict__ X,
    const float* __restrict__ bias,
    const float* __restrict__ scale, const float* __restrict__ shift)
{
    size_t i = (size_t)blockIdx.x * 256 + threadIdx.x;   // float4 index
    if (i >= (size_t)N_NODES * 64) return;
    int c4 = (int)(i & 63) * 4;
    float4 r = *(float4*)&outf[i * 4];
    float4 x = *(const float4*)&X[i * 4];
    float4 b = *(const float4*)&bias[c4];
    float4 sc = *(const float4*)&scale[c4];
    float4 sh = *(const float4*)&shift[c4];
    float4 o;
    o.x = fmaxf((r.x + x.x + b.x) * sc.x + sh.x, 0.f);
    o.y = fmaxf((r.y + x.y + b.y) * sc.y + sh.y, 0.f);
    o.z = fmaxf((r.z + x.z + b.z) * sc.z + sh.z, 0.f);
    o.w = fmaxf((r.w + x.w + b.w) * sc.w + sh.w, 0.f);
    *(float4*)&outf[i * 4] = o;
}

extern "C" void kernel_launch(void* const* d_in, const int* in_sizes, int n_in,
                              void* d_out, int out_size, void* d_ws, size_t ws_size,
                              hipStream_t stream) {
    const float* X      = (const float*)d_in[0];
    const int*   src    = (const int*)d_in[1];
    const int*   dst    = (const int*)d_in[2];
    const float* Wsrc   = (const float*)d_in[3];
    const float* bsrc   = (const float*)d_in[4];
    const float* Wdst   = (const float*)d_in[5];
    const float* bdst   = (const float*)d_in[6];
    const float* attn_w = (const float*)d_in[7];
    const float* bias   = (const float*)d_in[8];
    const float* gamma  = (const float*)d_in[9];
    const float* beta   = (const float*)d_in[10];

    float* out      = (float*)d_out;                       // [N,256] rst accumulator then final
    float* attn_out = out + (size_t)N_NODES * NFEAT;       // [E,4]

    float*    ws     = (float*)d_ws;
    float*    fs     = ws;                                  // N*256
    float*    fd     = fs + (size_t)N_NODES * NFEAT;        // N*256
    float*    logits = fd + (size_t)N_NODES * NFEAT;        // E*4 (logits then ex)
    unsigned* m_u    = (unsigned*)(logits + (size_t)N_EDGES * HEADS);  // N*4
    float*    ssum   = (float*)(m_u + (size_t)N_NODES * HEADS);        // N*4
    float*    csum   = ssum + (size_t)N_NODES * HEADS;      // 256
    float*    csumsq = csum + 256;                          // 256
    float*    scale  = csumsq + 256;                        // 256
    float*    shift  = scale + 256;                         // 256

    hipMemsetAsync(out,  0, (size_t)N_NODES * NFEAT * sizeof(float), stream);
    hipMemsetAsync(m_u,  0, (size_t)N_NODES * HEADS * sizeof(unsigned), stream); // 0 < f2mono(any float)
    hipMemsetAsync(ssum, 0, (size_t)N_NODES * HEADS * sizeof(float), stream);
    hipMemsetAsync(csum, 0, 2 * 256 * sizeof(float), stream);

    proj_gemm<<<dim3((N_NODES + BM - 1) / BM, 8), 256, 0, stream>>>(
        X, Wsrc, bsrc, Wdst, bdst, fs, fd);
    edge_logits<<<(N_EDGES + 3) / 4, 256, 0, stream>>>(
        fs, fd, src, dst, attn_w, logits, m_u);
    edge_exp<<<(N_EDGES * HEADS + 255) / 256, 256, 0, stream>>>(
        dst, logits, m_u, ssum);
    edge_aggr<<<(N_EDGES + 3) / 4, 256, 0, stream>>>(
        fs, src, dst, logits, ssum, attn_out, out);
    colstats<<<512, 256, 0, stream>>>(out, X, bias, csum, csumsq);
    finalize_stats<<<1, 256, 0, stream>>>(csum, csumsq, gamma, beta, scale, shift);
    bn_relu<<<(N_NODES * 64 + 255) / 256, 256, 0, stream>>>(
        out, X, bias, scale, shift);
}

// Round 3
// 669.732 us; speedup vs baseline: 4.9158x; 4.9158x over previous
//
#include <hip/hip_runtime.h>
#include <hip/hip_bf16.h>
#include <cfloat>

// GATv2 layer pipeline (round 2: CSR gather + fused online-softmax aggregation):
//   1) proj_gemm: fs = X@Wsrc+bsrc, fd = X@Wdst+bdst   (f32 tiled GEMM, unchanged)
//   2) CSR build by dst: count_deg -> scan_deg (single-block) -> scatter_edges
//   3) fused_node: one wave per node, online softmax over incoming edges,
//      acc = sum fs[src]*exp(logit-m)/ssum, writes out = acc + X + bias,
//      stores per-(node,head) m and 1/ssum, stores raw logits per edge
//   4) attn_norm: a[e,h] = exp(logit - m[dst]) * inv[dst]
//   5) colstats + finalize_stats + bn_relu: BatchNorm(train stats) + ReLU

#define N_NODES 50000
#define N_EDGES 800000
#define NFEAT 256
#define HEADS 4
#define HDIM 64
#define NEG_SLOPE 0.2f
#define BN_EPS 1e-5f

// ---------------- 1) projection GEMM (f32) ----------------
#define BM 128
#define BN 64
#define BK 16

__global__ __launch_bounds__(256) void proj_gemm(
    const float* __restrict__ X,
    const float* __restrict__ Wsrc, const float* __restrict__ bsrc,
    const float* __restrict__ Wdst, const float* __restrict__ bdst,
    float* __restrict__ fs, float* __restrict__ fd)
{
    const int bm = blockIdx.x;
    const int bn = blockIdx.y;     // 0..7 : 0-3 -> fs, 4-7 -> fd
    const float* W;  const float* bvec;  float* out;  int ncol0;
    if (bn < 4) { W = Wsrc; bvec = bsrc; out = fs; ncol0 = bn * 64; }
    else        { W = Wdst; bvec = bdst; out = fd; ncol0 = (bn - 4) * 64; }

    __shared__ float As[BK][BM + 4];
    __shared__ float Bs[BK][BN];

    const int tid = threadIdx.x;
    const int tm = (tid >> 4) * 8;   // 0..120
    const int tn = (tid & 15) * 4;   // 0..60
    const int row0 = bm * BM;

    float acc[8][4] = {};

    for (int k0 = 0; k0 < NFEAT; k0 += BK) {
        #pragma unroll
        for (int i = 0; i < 2; i++) {
            int idx = tid + i * 256;           // 0..511
            int r = idx >> 2;                  // 0..127
            int kq = (idx & 3) * 4;            // 0,4,8,12
            float4 v = make_float4(0.f, 0.f, 0.f, 0.f);
            int gr = row0 + r;
            if (gr < N_NODES)
                v = *(const float4*)&X[(size_t)gr * NFEAT + k0 + kq];
            As[kq + 0][r] = v.x; As[kq + 1][r] = v.y;
            As[kq + 2][r] = v.z; As[kq + 3][r] = v.w;
        }
        {
            int kr = tid >> 4;                 // 0..15
            int nq = (tid & 15) * 4;           // 0..60
            float4 v = *(const float4*)&W[(size_t)(k0 + kr) * (HEADS * HDIM) + ncol0 + nq];
            *(float4*)&Bs[kr][nq] = v;
        }
        __syncthreads();

        #pragma unroll
        for (int kk = 0; kk < BK; kk++) {
            float a0[8];
            #pragma unroll
            for (int i = 0; i < 8; i++) a0[i] = As[kk][tm + i];
            float4 b4 = *(float4*)&Bs[kk][tn];
            float b[4] = { b4.x, b4.y, b4.z, b4.w };
            #pragma unroll
            for (int i = 0; i < 8; i++)
                #pragma unroll
                for (int j = 0; j < 4; j++)
                    acc[i][j] += a0[i] * b[j];
        }
        __syncthreads();
    }

    float4 bb = *(const float4*)&bvec[ncol0 + tn];
    #pragma unroll
    for (int i = 0; i < 8; i++) {
        int gr = row0 + tm + i;
        if (gr < N_NODES) {
            float4 v;
            v.x = acc[i][0] + bb.x;
            v.y = acc[i][1] + bb.y;
            v.z = acc[i][2] + bb.z;
            v.w = acc[i][3] + bb.w;
            *(float4*)&out[(size_t)gr * NFEAT + ncol0 + tn] = v;
        }
    }
}

// ---------------- 2) CSR build by dst ----------------
__global__ __launch_bounds__(256) void count_deg(
    const int* __restrict__ dst, int* __restrict__ deg)
{
    int e = blockIdx.x * 256 + threadIdx.x;
    if (e < N_EDGES) atomicAdd(&deg[dst[e]], 1);
}

// single block, 1024 threads: exclusive prefix sum of deg -> row_start[N+1]
__global__ __launch_bounds__(1024) void scan_deg(
    const int* __restrict__ deg, int* __restrict__ row_start)
{
    __shared__ int sums[1024];
    const int t = threadIdx.x;
    const int CH = (N_NODES + 1023) / 1024;   // 49
    int lo = t * CH, hi = min(lo + CH, N_NODES);
    int s = 0;
    for (int i = lo; i < hi; i++) s += deg[i];
    sums[t] = s;
    __syncthreads();
    // Hillis-Steele inclusive scan
    for (int off = 1; off < 1024; off <<= 1) {
        int v = (t >= off) ? sums[t - off] : 0;
        __syncthreads();
        sums[t] += v;
        __syncthreads();
    }
    int run = sums[t] - s;   // exclusive prefix of this chunk
    for (int i = lo; i < hi; i++) { row_start[i] = run; run += deg[i]; }
    if (t == 0) row_start[N_NODES] = N_EDGES;
}

__global__ __launch_bounds__(256) void scatter_edges(
    const int* __restrict__ dst, const int* __restrict__ row_start,
    int* __restrict__ fill, int* __restrict__ eid)
{
    int e = blockIdx.x * 256 + threadIdx.x;
    if (e >= N_EDGES) return;
    int d = dst[e];
    int pos = row_start[d] + atomicAdd(&fill[d], 1);
    eid[pos] = e;
}

// ---------------- 3) fused per-node online-softmax aggregation ----------------
// one wave per node; lane handles dims 4*lane..4*lane+3; head = lane>>4
__global__ __launch_bounds__(256) void fused_node(
    const float* __restrict__ fs, const float* __restrict__ fd,
    const float* __restrict__ X, const float* __restrict__ bias,
    const int* __restrict__ row_start, const int* __restrict__ eid,
    const int* __restrict__ src, const float* __restrict__ attn_w,
    float* __restrict__ logits, float* __restrict__ m_buf,
    float* __restrict__ inv_buf, float* __restrict__ out)
{
    int n = blockIdx.x * 4 + (threadIdx.x >> 6);
    if (n >= N_NODES) return;
    int lane = threadIdx.x & 63;
    int h = lane >> 4;

    float4 fdv = *(const float4*)&fd[(size_t)n * NFEAT + lane * 4];
    float4 w   = *(const float4*)&attn_w[lane * 4];

    float m = -INFINITY, ssum = 0.f;
    float4 acc = make_float4(0.f, 0.f, 0.f, 0.f);

    int s0 = row_start[n], s1 = row_start[n + 1];
    for (int i = s0; i < s1; ++i) {
        int e = eid[i];
        int si = src[e];
        float4 u = *(const float4*)&fs[(size_t)si * NFEAT + lane * 4];
        float p = 0.f, x;
        x = u.x + fdv.x; x = x > 0.f ? x : NEG_SLOPE * x; p += x * w.x;
        x = u.y + fdv.y; x = x > 0.f ? x : NEG_SLOPE * x; p += x * w.y;
        x = u.z + fdv.z; x = x > 0.f ? x : NEG_SLOPE * x; p += x * w.z;
        x = u.w + fdv.w; x = x > 0.f ? x : NEG_SLOPE * x; p += x * w.w;
        // butterfly sum over the 16-lane head group -> p is full logit in ALL lanes
        #pragma unroll
        for (int off = 8; off; off >>= 1) p += __shfl_xor(p, off, 16);
        if ((lane & 15) == 0) logits[(size_t)e * HEADS + h] = p;
        // online softmax update
        float mn = fmaxf(m, p);
        float sc = __expf(m - mn);    // exp(-inf)=0 on first edge
        float ex = __expf(p - mn);
        ssum = ssum * sc + ex;
        acc.x = acc.x * sc + u.x * ex;
        acc.y = acc.y * sc + u.y * ex;
        acc.z = acc.z * sc + u.z * ex;
        acc.w = acc.w * sc + u.w * ex;
        m = mn;
    }
    float inv = ssum > 0.f ? 1.f / ssum : 0.f;
    if ((lane & 15) == 0) {
        m_buf[(size_t)n * HEADS + h] = m;
        inv_buf[(size_t)n * HEADS + h] = inv;
    }
    float4 xr = *(const float4*)&X[(size_t)n * NFEAT + lane * 4];
    float4 bb = *(const float4*)&bias[lane * 4];
    float4 o;
    o.x = acc.x * inv + xr.x + bb.x;
    o.y = acc.y * inv + xr.y + bb.y;
    o.z = acc.z * inv + xr.z + bb.z;
    o.w = acc.w * inv + xr.w + bb.w;
    *(float4*)&out[(size_t)n * NFEAT + lane * 4] = o;
}

// ---------------- 4) attention output ----------------
__global__ __launch_bounds__(256) void attn_norm(
    const int* __restrict__ dst, const float* __restrict__ logits,
    const float* __restrict__ m_buf, const float* __restrict__ inv_buf,
    float* __restrict__ attn_out)
{
    int idx = blockIdx.x * 256 + threadIdx.x;
    if (idx >= N_EDGES * HEADS) return;
    int e = idx >> 2, h = idx & 3;
    int d = dst[e];
    attn_out[idx] = __expf(logits[idx] - m_buf[(size_t)d * HEADS + h])
                    * inv_buf[(size_t)d * HEADS + h];
}

// ---------------- 5) BatchNorm stats ----------------
__global__ __launch_bounds__(256) void colstats(
    const float* __restrict__ outf,
    float* __restrict__ csum, float* __restrict__ csumsq)
{
    int c = threadIdx.x;
    float s0 = 0.f, s1 = 0.f;
    for (int r = blockIdx.x; r < N_NODES; r += gridDim.x) {
        float v = outf[(size_t)r * NFEAT + c];
        s0 += v; s1 += v * v;
    }
    atomicAdd(&csum[c], s0);
    atomicAdd(&csumsq[c], s1);
}

__global__ void finalize_stats(
    const float* __restrict__ csum, const float* __restrict__ csumsq,
    const float* __restrict__ gamma, const float* __restrict__ beta,
    float* __restrict__ scale, float* __restrict__ shift)
{
    int c = threadIdx.x;
    float mean = csum[c] * (1.0f / N_NODES);
    float var = csumsq[c] * (1.0f / N_NODES) - mean * mean;
    float sc = gamma[c] * rsqrtf(var + BN_EPS);
    scale[c] = sc;
    shift[c] = beta[c] - mean * sc;
}

__global__ __launch_bounds__(256) void bn_relu(
    float* __restrict__ outf,
    const float* __restrict__ scale, const float* __restrict__ shift)
{
    size_t i = (size_t)blockIdx.x * 256 + threadIdx.x;   // float4 index
    if (i >= (size_t)N_NODES * 64) return;
    int c4 = (int)(i & 63) * 4;
    float4 r = *(float4*)&outf[i * 4];
    float4 sc = *(const float4*)&scale[c4];
    float4 sh = *(const float4*)&shift[c4];
    float4 o;
    o.x = fmaxf(r.x * sc.x + sh.x, 0.f);
    o.y = fmaxf(r.y * sc.y + sh.y, 0.f);
    o.z = fmaxf(r.z * sc.z + sh.z, 0.f);
    o.w = fmaxf(r.w * sc.w + sh.w, 0.f);
    *(float4*)&outf[i * 4] = o;
}

extern "C" void kernel_launch(void* const* d_in, const int* in_sizes, int n_in,
                              void* d_out, int out_size, void* d_ws, size_t ws_size,
                              hipStream_t stream) {
    const float* X      = (const float*)d_in[0];
    const int*   src    = (const int*)d_in[1];
    const int*   dst    = (const int*)d_in[2];
    const float* Wsrc   = (const float*)d_in[3];
    const float* bsrc   = (const float*)d_in[4];
    const float* Wdst   = (const float*)d_in[5];
    const float* bdst   = (const float*)d_in[6];
    const float* attn_w = (const float*)d_in[7];
    const float* bias   = (const float*)d_in[8];
    const float* gamma  = (const float*)d_in[9];
    const float* beta   = (const float*)d_in[10];

    float* out      = (float*)d_out;                       // [N,256]
    float* attn_out = out + (size_t)N_NODES * NFEAT;       // [E,4]

    float*    ws      = (float*)d_ws;
    float*    fs      = ws;                                  // N*256
    float*    fd      = fs + (size_t)N_NODES * NFEAT;        // N*256
    float*    logits  = fd + (size_t)N_NODES * NFEAT;        // E*4
    float*    m_buf   = logits + (size_t)N_EDGES * HEADS;    // N*4
    float*    inv_buf = m_buf + (size_t)N_NODES * HEADS;     // N*4
    float*    csum    = inv_buf + (size_t)N_NODES * HEADS;   // 256
    float*    csumsq  = csum + 256;                          // 256
    float*    scale   = csumsq + 256;                        // 256
    float*    shift   = scale + 256;                         // 256
    int*      deg     = (int*)(shift + 256);                 // N
    int*      row_start = deg + N_NODES;                     // N+1
    int*      fill    = row_start + N_NODES + 1;             // N
    int*      eid     = fill + N_NODES;                      // E

    hipMemsetAsync(deg,  0, N_NODES * sizeof(int), stream);
    hipMemsetAsync(fill, 0, N_NODES * sizeof(int), stream);
    hipMemsetAsync(csum, 0, 2 * 256 * sizeof(float), stream);

    proj_gemm<<<dim3((N_NODES + BM - 1) / BM, 8), 256, 0, stream>>>(
        X, Wsrc, bsrc, Wdst, bdst, fs, fd);
    count_deg<<<(N_EDGES + 255) / 256, 256, 0, stream>>>(dst, deg);
    scan_deg<<<1, 1024, 0, stream>>>(deg, row_start);
    scatter_edges<<<(N_EDGES + 255) / 256, 256, 0, stream>>>(dst, row_start, fill, eid);
    fused_node<<<(N_NODES + 3) / 4, 256, 0, stream>>>(
        fs, fd, X, bias, row_start, eid, src, attn_w,
        logits, m_buf, inv_buf, out);
    attn_norm<<<(N_EDGES * HEADS + 255) / 256, 256, 0, stream>>>(
        dst, logits, m_buf, inv_buf, attn_out);
    colstats<<<512, 256, 0, stream>>>(out, csum, csumsq);
    finalize_stats<<<1, 256, 0, stream>>>(csum, csumsq, gamma, beta, scale, shift);
    bn_relu<<<(N_NODES * 64 + 255) / 256, 256, 0, stream>>>(out, scale, shift);
}

// Round 4
// 576.049 us; speedup vs baseline: 5.7153x; 1.1626x over previous
//
#include <hip/hip_runtime.h>
#include <hip/hip_bf16.h>
#include <cfloat>

// GATv2 layer pipeline (round 3: bf16 MFMA projection + bf16 gathers):
//   0) cvt_x: X f32 -> Xb bf16 ; prep_wt: WT[n][k] = bf16(W[k][n]) for [Wsrc|Wdst]
//   1) proj_mfma: fsb/fdb = bf16(Xb @ W + b)  via mfma_f32_16x16x32_bf16
//   2) CSR build by dst: count_deg -> scan_deg -> scatter_edges
//   3) fused_node: one wave per node, online softmax over incoming edges (bf16 gathers)
//   4) attn_norm: a[e,h] = exp(logit - m[dst]) * inv[dst]
//   5) colstats + finalize_stats + bn_relu

#define N_NODES 50000
#define N_EDGES 800000
#define NFEAT 256
#define HEADS 4
#define NEG_SLOPE 0.2f
#define BN_EPS 1e-5f

typedef __attribute__((ext_vector_type(8))) short bf16x8;
typedef __attribute__((ext_vector_type(4))) float f32x4;
typedef __attribute__((ext_vector_type(8))) unsigned short u16x8;

__device__ __forceinline__ float bf2f(unsigned short u) {
    return __uint_as_float(((unsigned)u) << 16);
}
__device__ __forceinline__ unsigned short f2bf(float f) {
    unsigned u = __float_as_uint(f);
    unsigned r = u + 0x7FFFu + ((u >> 16) & 1u);
    return (unsigned short)(r >> 16);
}

// ---------------- 0) conversions ----------------
__global__ __launch_bounds__(256) void cvt_x(
    const float* __restrict__ X, ushort* __restrict__ Xb)
{
    size_t i = (size_t)blockIdx.x * 256 + threadIdx.x;   // float4 index
    if (i >= (size_t)N_NODES * 64) return;
    float4 v = *(const float4*)&X[i * 4];
    ushort4 o;
    o.x = f2bf(v.x); o.y = f2bf(v.y); o.z = f2bf(v.z); o.w = f2bf(v.w);
    *(ushort4*)&Xb[i * 4] = o;
}

// WT[n][k] = bf16(W[k][n]); n in [0,512): 0-255 Wsrc cols, 256-511 Wdst cols
__global__ __launch_bounds__(256) void prep_wt(
    const float* __restrict__ Wsrc, const float* __restrict__ Wdst,
    ushort* __restrict__ WT)
{
    int n = blockIdx.x;
    int k = threadIdx.x;
    const float* W = (n < 256) ? Wsrc : Wdst;
    int nc = n & 255;
    WT[(size_t)n * 256 + k] = f2bf(W[(size_t)k * 256 + nc]);
}

// ---------------- 1) MFMA projection GEMM ----------------
// grid (ceil(N/128), 8); block 256 = 4 waves; tile 128x64; B panel LDS-resident.
__global__ __launch_bounds__(256) void proj_mfma(
    const ushort* __restrict__ Xb, const ushort* __restrict__ WT,
    const float* __restrict__ bsrc, const float* __restrict__ bdst,
    ushort* __restrict__ fsb, ushort* __restrict__ fdb)
{
    __shared__ alignas(16) ushort Bs[64][264];   // [n][k], pad->16B aligned rows, 2-way bank max
    __shared__ alignas(16) ushort As[128][40];   // [row][k within step], 16B aligned rows

    const int tid = threadIdx.x;
    const int row0 = blockIdx.x * 128;
    const int bn = blockIdx.y;                 // 0..7 over concat [fs|fd] cols
    const int ncol0 = bn * 64;                 // concat col base
    const float* bvec = (bn < 4) ? bsrc : bdst;
    ushort* outp = (bn < 4) ? fsb : fdb;
    const int col_base = (bn & 3) * 64;        // within 256

    // preload B panel: 64 n-rows x 256 k
    {
        int n = tid >> 2;
        int kc = (tid & 3) * 64;
        const ushort* srcp = &WT[(size_t)(ncol0 + n) * 256 + kc];
        #pragma unroll
        for (int j = 0; j < 8; j++) {
            u16x8 v = *(const u16x8*)(srcp + j * 8);
            *(u16x8*)&Bs[n][kc + j * 8] = v;
        }
    }

    const int wid = tid >> 6, lane = tid & 63;
    const int l15 = lane & 15, lg = lane >> 4;

    f32x4 acc[2][4] = {};

    for (int k0 = 0; k0 < 256; k0 += 32) {
        __syncthreads();   // As reuse guard; also covers Bs readiness on first iter
        #pragma unroll
        for (int i = 0; i < 2; i++) {
            int idx = tid + i * 256;           // 0..511
            int r = idx >> 2, c8 = (idx & 3) * 8;
            int gr = row0 + r;
            u16x8 v = 0;
            if (gr < N_NODES) v = *(const u16x8*)&Xb[(size_t)gr * 256 + k0 + c8];
            *(u16x8*)&As[r][c8] = v;
        }
        __syncthreads();

        bf16x8 af[2], bfr[4];
        #pragma unroll
        for (int rt = 0; rt < 2; rt++)
            af[rt] = *(const bf16x8*)&As[wid * 32 + rt * 16 + l15][lg * 8];
        #pragma unroll
        for (int ct = 0; ct < 4; ct++)
            bfr[ct] = *(const bf16x8*)&Bs[ct * 16 + l15][k0 + lg * 8];
        #pragma unroll
        for (int rt = 0; rt < 2; rt++)
            #pragma unroll
            for (int ct = 0; ct < 4; ct++)
                acc[rt][ct] = __builtin_amdgcn_mfma_f32_16x16x32_bf16(
                    af[rt], bfr[ct], acc[rt][ct], 0, 0, 0);
    }

    // epilogue: D[row = (lg*4+reg) within 16-tile][col = l15]
    #pragma unroll
    for (int rt = 0; rt < 2; rt++) {
        #pragma unroll
        for (int ct = 0; ct < 4; ct++) {
            int col = col_base + ct * 16 + l15;
            float bb = bvec[col];
            #pragma unroll
            for (int r = 0; r < 4; r++) {
                int row = row0 + wid * 32 + rt * 16 + lg * 4 + r;
                if (row < N_NODES)
                    outp[(size_t)row * 256 + col] = f2bf(acc[rt][ct][r] + bb);
            }
        }
    }
}

// ---------------- 2) CSR build by dst ----------------
__global__ __launch_bounds__(256) void count_deg(
    const int* __restrict__ dst, int* __restrict__ deg)
{
    int e = blockIdx.x * 256 + threadIdx.x;
    if (e < N_EDGES) atomicAdd(&deg[dst[e]], 1);
}

__global__ __launch_bounds__(1024) void scan_deg(
    const int* __restrict__ deg, int* __restrict__ row_start)
{
    __shared__ int sums[1024];
    const int t = threadIdx.x;
    const int CH = (N_NODES + 1023) / 1024;   // 49
    int lo = t * CH, hi = min(lo + CH, N_NODES);
    int s = 0;
    for (int i = lo; i < hi; i++) s += deg[i];
    sums[t] = s;
    __syncthreads();
    for (int off = 1; off < 1024; off <<= 1) {
        int v = (t >= off) ? sums[t - off] : 0;
        __syncthreads();
        sums[t] += v;
        __syncthreads();
    }
    int run = sums[t] - s;
    for (int i = lo; i < hi; i++) { row_start[i] = run; run += deg[i]; }
    if (t == 0) row_start[N_NODES] = N_EDGES;
}

__global__ __launch_bounds__(256) void scatter_edges(
    const int* __restrict__ dst, const int* __restrict__ row_start,
    int* __restrict__ fill, int* __restrict__ eid)
{
    int e = blockIdx.x * 256 + threadIdx.x;
    if (e >= N_EDGES) return;
    int d = dst[e];
    int pos = row_start[d] + atomicAdd(&fill[d], 1);
    eid[pos] = e;
}

// ---------------- 3) fused per-node online-softmax aggregation ----------------
__global__ __launch_bounds__(256) void fused_node(
    const ushort* __restrict__ fsb, const ushort* __restrict__ fdb,
    const float* __restrict__ X, const float* __restrict__ bias,
    const int* __restrict__ row_start, const int* __restrict__ eid,
    const int* __restrict__ src, const float* __restrict__ attn_w,
    float* __restrict__ logits, float* __restrict__ m_buf,
    float* __restrict__ inv_buf, float* __restrict__ out)
{
    int n = blockIdx.x * 4 + (threadIdx.x >> 6);
    if (n >= N_NODES) return;
    int lane = threadIdx.x & 63;
    int h = lane >> 4;

    ushort4 fd4 = *(const ushort4*)&fdb[(size_t)n * 256 + lane * 4];
    float fdx = bf2f(fd4.x), fdy = bf2f(fd4.y), fdz = bf2f(fd4.z), fdw = bf2f(fd4.w);
    float4 w = *(const float4*)&attn_w[lane * 4];

    float m = -INFINITY, ssum = 0.f;
    float4 acc = make_float4(0.f, 0.f, 0.f, 0.f);

    int s0 = row_start[n], s1 = row_start[n + 1];
    for (int i = s0; i < s1; ++i) {
        int e = eid[i];
        int si = src[e];
        ushort4 u4 = *(const ushort4*)&fsb[(size_t)si * 256 + lane * 4];
        float ux = bf2f(u4.x), uy = bf2f(u4.y), uz = bf2f(u4.z), uw = bf2f(u4.w);
        float p = 0.f, x;
        x = ux + fdx; x = x > 0.f ? x : NEG_SLOPE * x; p += x * w.x;
        x = uy + fdy; x = x > 0.f ? x : NEG_SLOPE * x; p += x * w.y;
        x = uz + fdz; x = x > 0.f ? x : NEG_SLOPE * x; p += x * w.z;
        x = uw + fdw; x = x > 0.f ? x : NEG_SLOPE * x; p += x * w.w;
        #pragma unroll
        for (int off = 8; off; off >>= 1) p += __shfl_xor(p, off, 16);
        if ((lane & 15) == 0) logits[(size_t)e * HEADS + h] = p;
        float mn = fmaxf(m, p);
        float sc = __expf(m - mn);
        float ex = __expf(p - mn);
        ssum = ssum * sc + ex;
        acc.x = acc.x * sc + ux * ex;
        acc.y = acc.y * sc + uy * ex;
        acc.z = acc.z * sc + uz * ex;
        acc.w = acc.w * sc + uw * ex;
        m = mn;
    }
    float inv = ssum > 0.f ? 1.f / ssum : 0.f;
    if ((lane & 15) == 0) {
        m_buf[(size_t)n * HEADS + h] = m;
        inv_buf[(size_t)n * HEADS + h] = inv;
    }
    float4 xr = *(const float4*)&X[(size_t)n * NFEAT + lane * 4];
    float4 bb = *(const float4*)&bias[lane * 4];
    float4 o;
    o.x = acc.x * inv + xr.x + bb.x;
    o.y = acc.y * inv + xr.y + bb.y;
    o.z = acc.z * inv + xr.z + bb.z;
    o.w = acc.w * inv + xr.w + bb.w;
    *(float4*)&out[(size_t)n * NFEAT + lane * 4] = o;
}

// ---------------- 4) attention output ----------------
__global__ __launch_bounds__(256) void attn_norm(
    const int* __restrict__ dst, const float* __restrict__ logits,
    const float* __restrict__ m_buf, const float* __restrict__ inv_buf,
    float* __restrict__ attn_out)
{
    int idx = blockIdx.x * 256 + threadIdx.x;
    if (idx >= N_EDGES * HEADS) return;
    int e = idx >> 2, h = idx & 3;
    int d = dst[e];
    attn_out[idx] = __expf(logits[idx] - m_buf[(size_t)d * HEADS + h])
                    * inv_buf[(size_t)d * HEADS + h];
}

// ---------------- 5) BatchNorm ----------------
__global__ __launch_bounds__(256) void colstats(
    const float* __restrict__ outf,
    float* __restrict__ csum, float* __restrict__ csumsq)
{
    int c = threadIdx.x;
    float s0 = 0.f, s1 = 0.f;
    for (int r = blockIdx.x; r < N_NODES; r += gridDim.x) {
        float v = outf[(size_t)r * NFEAT + c];
        s0 += v; s1 += v * v;
    }
    atomicAdd(&csum[c], s0);
    atomicAdd(&csumsq[c], s1);
}

__global__ void finalize_stats(
    const float* __restrict__ csum, const float* __restrict__ csumsq,
    const float* __restrict__ gamma, const float* __restrict__ beta,
    float* __restrict__ scale, float* __restrict__ shift)
{
    int c = threadIdx.x;
    float mean = csum[c] * (1.0f / N_NODES);
    float var = csumsq[c] * (1.0f / N_NODES) - mean * mean;
    float sc = gamma[c] * rsqrtf(var + BN_EPS);
    scale[c] = sc;
    shift[c] = beta[c] - mean * sc;
}

__global__ __launch_bounds__(256) void bn_relu(
    float* __restrict__ outf,
    const float* __restrict__ scale, const float* __restrict__ shift)
{
    size_t i = (size_t)blockIdx.x * 256 + threadIdx.x;
    if (i >= (size_t)N_NODES * 64) return;
    int c4 = (int)(i & 63) * 4;
    float4 r = *(float4*)&outf[i * 4];
    float4 sc = *(const float4*)&scale[c4];
    float4 sh = *(const float4*)&shift[c4];
    float4 o;
    o.x = fmaxf(r.x * sc.x + sh.x, 0.f);
    o.y = fmaxf(r.y * sc.y + sh.y, 0.f);
    o.z = fmaxf(r.z * sc.z + sh.z, 0.f);
    o.w = fmaxf(r.w * sc.w + sh.w, 0.f);
    *(float4*)&outf[i * 4] = o;
}

extern "C" void kernel_launch(void* const* d_in, const int* in_sizes, int n_in,
                              void* d_out, int out_size, void* d_ws, size_t ws_size,
                              hipStream_t stream) {
    const float* X      = (const float*)d_in[0];
    const int*   src    = (const int*)d_in[1];
    const int*   dst    = (const int*)d_in[2];
    const float* Wsrc   = (const float*)d_in[3];
    const float* bsrc   = (const float*)d_in[4];
    const float* Wdst   = (const float*)d_in[5];
    const float* bdst   = (const float*)d_in[6];
    const float* attn_w = (const float*)d_in[7];
    const float* bias   = (const float*)d_in[8];
    const float* gamma  = (const float*)d_in[9];
    const float* beta   = (const float*)d_in[10];

    float* out      = (float*)d_out;                       // [N,256]
    float* attn_out = out + (size_t)N_NODES * NFEAT;       // [E,4]

    char* w = (char*)d_ws;
    ushort* Xb   = (ushort*)w;  w += (size_t)N_NODES * 256 * 2;
    ushort* fsb  = (ushort*)w;  w += (size_t)N_NODES * 256 * 2;
    ushort* fdb  = (ushort*)w;  w += (size_t)N_NODES * 256 * 2;
    ushort* WT   = (ushort*)w;  w += (size_t)512 * 256 * 2;
    float* logits  = (float*)w; w += (size_t)N_EDGES * HEADS * 4;
    float* m_buf   = (float*)w; w += (size_t)N_NODES * HEADS * 4;
    float* inv_buf = (float*)w; w += (size_t)N_NODES * HEADS * 4;
    float* csum    = (float*)w; w += 256 * 4;
    float* csumsq  = (float*)w; w += 256 * 4;
    float* scale   = (float*)w; w += 256 * 4;
    float* shift   = (float*)w; w += 256 * 4;
    int* deg       = (int*)w;   w += (size_t)N_NODES * 4;
    int* row_start = (int*)w;   w += (size_t)(N_NODES + 1) * 4;
    int* fill      = (int*)w;   w += (size_t)N_NODES * 4;
    int* eid       = (int*)w;   w += (size_t)N_EDGES * 4;

    hipMemsetAsync(deg,  0, N_NODES * sizeof(int), stream);
    hipMemsetAsync(fill, 0, N_NODES * sizeof(int), stream);
    hipMemsetAsync(csum, 0, 2 * 256 * sizeof(float), stream);

    cvt_x<<<(N_NODES * 64 + 255) / 256, 256, 0, stream>>>(X, Xb);
    prep_wt<<<512, 256, 0, stream>>>(Wsrc, Wdst, WT);
    proj_mfma<<<dim3((N_NODES + 127) / 128, 8), 256, 0, stream>>>(
        Xb, WT, bsrc, bdst, fsb, fdb);
    count_deg<<<(N_EDGES + 255) / 256, 256, 0, stream>>>(dst, deg);
    scan_deg<<<1, 1024, 0, stream>>>(deg, row_start);
    scatter_edges<<<(N_EDGES + 255) / 256, 256, 0, stream>>>(dst, row_start, fill, eid);
    fused_node<<<(N_NODES + 3) / 4, 256, 0, stream>>>(
        fsb, fdb, X, bias, row_start, eid, src, attn_w,
        logits, m_buf, inv_buf, out);
    attn_norm<<<(N_EDGES * HEADS + 255) / 256, 256, 0, stream>>>(
        dst, logits, m_buf, inv_buf, attn_out);
    colstats<<<512, 256, 0, stream>>>(out, csum, csumsq);
    finalize_stats<<<1, 256, 0, stream>>>(csum, csumsq, gamma, beta, scale, shift);
    bn_relu<<<(N_NODES * 64 + 255) / 256, 256, 0, stream>>>(out, scale, shift);
}

// Round 5
// 512.617 us; speedup vs baseline: 6.4225x; 1.1237x over previous
//
#include <hip/hip_runtime.h>
#include <hip/hip_bf16.h>
#include <cfloat>

// GATv2 layer pipeline (round 5):
//   0) prep_wt: WT[n][k] = bf16(W[k][n]) for [Wsrc|Wdst] (512x256)
//   1) proj_mfma: 128x256 tile per block, reads X f32 + converts in staging,
//      fs/fd = bf16(X @ W + b) via mfma_f32_16x16x32_bf16
//   2) CSR build: count_deg -> 3-kernel block scan -> scatter_edges
//      (stores src_csr / eid_csr / dstn_csr)
//   3) fused_node: wave/node online softmax, 4-edge unrolled gathers
//      logits written in CSR order (coalesced)
//   4) attn_norm: CSR-order read, scatter write to attn_out[eid]
//   5) colstats + finalize_stats + bn_relu

#define N_NODES 50000
#define N_EDGES 800000
#define NFEAT 256
#define HEADS 4
#define NEG_SLOPE 0.2f
#define BN_EPS 1e-5f
#define NB_SCAN 196   // ceil(50000/256)

typedef __attribute__((ext_vector_type(8))) short bf16x8;
typedef __attribute__((ext_vector_type(4))) float f32x4;
typedef __attribute__((ext_vector_type(8))) unsigned short u16x8;

__device__ __forceinline__ float bf2f(unsigned short u) {
    return __uint_as_float(((unsigned)u) << 16);
}
__device__ __forceinline__ unsigned short f2bf(float f) {
    unsigned u = __float_as_uint(f);
    unsigned r = u + 0x7FFFu + ((u >> 16) & 1u);
    return (unsigned short)(r >> 16);
}

// ---------------- 0) weight transpose+convert ----------------
__global__ __launch_bounds__(256) void prep_wt(
    const float* __restrict__ Wsrc, const float* __restrict__ Wdst,
    ushort* __restrict__ WT)
{
    int n = blockIdx.x;
    int k = threadIdx.x;
    const float* W = (n < 256) ? Wsrc : Wdst;
    int nc = n & 255;
    WT[(size_t)n * 256 + k] = f2bf(W[(size_t)k * 256 + nc]);
}

// ---------------- 1) MFMA projection GEMM ----------------
// grid (391, 2); block 256 = 4 waves; tile 128 rows x 256 cols.
__global__ __launch_bounds__(256) void proj_mfma(
    const float* __restrict__ X, const ushort* __restrict__ WT,
    const float* __restrict__ bsrc, const float* __restrict__ bdst,
    ushort* __restrict__ fsb, ushort* __restrict__ fdb)
{
    __shared__ alignas(16) ushort As[128][40];   // [row][k in step], pad 8
    __shared__ alignas(16) ushort Bs[256][40];   // [n][k in step]

    const int tid = threadIdx.x;
    const int row0 = blockIdx.x * 128;
    const int bn = blockIdx.y;                 // 0 -> fs, 1 -> fd
    const float* bvec = (bn == 0) ? bsrc : bdst;
    ushort* outp = (bn == 0) ? fsb : fdb;
    const int nbase = bn * 256;

    const int wid = tid >> 6, lane = tid & 63;
    const int l15 = lane & 15, lg = lane >> 4;

    // staging indices
    const int ar = tid >> 1;            // 0..127
    const int ah = (tid & 1) * 16;      // 0 / 16

    f32x4 acc[2][16] = {};

    for (int k0 = 0; k0 < 256; k0 += 32) {
        __syncthreads();   // guard LDS reuse
        // stage A: 128 rows x 32 k, f32 -> bf16 in-register
        {
            int gr = row0 + ar;
            float4 v0 = make_float4(0.f,0.f,0.f,0.f), v1 = v0, v2 = v0, v3 = v0;
            if (gr < N_NODES) {
                const float* p = &X[(size_t)gr * 256 + k0 + ah];
                v0 = *(const float4*)(p + 0);
                v1 = *(const float4*)(p + 4);
                v2 = *(const float4*)(p + 8);
                v3 = *(const float4*)(p + 12);
            }
            u16x8 o0, o1;
            o0[0]=f2bf(v0.x); o0[1]=f2bf(v0.y); o0[2]=f2bf(v0.z); o0[3]=f2bf(v0.w);
            o0[4]=f2bf(v1.x); o0[5]=f2bf(v1.y); o0[6]=f2bf(v1.z); o0[7]=f2bf(v1.w);
            o1[0]=f2bf(v2.x); o1[1]=f2bf(v2.y); o1[2]=f2bf(v2.z); o1[3]=f2bf(v2.w);
            o1[4]=f2bf(v3.x); o1[5]=f2bf(v3.y); o1[6]=f2bf(v3.z); o1[7]=f2bf(v3.w);
            *(u16x8*)&As[ar][ah + 0] = o0;
            *(u16x8*)&As[ar][ah + 8] = o1;
        }
        // stage B: 256 n x 32 k
        {
            const ushort* p = &WT[(size_t)(nbase + tid) * 256 + k0];
            #pragma unroll
            for (int j = 0; j < 4; j++)
                *(u16x8*)&Bs[tid][j * 8] = *(const u16x8*)(p + j * 8);
        }
        __syncthreads();

        bf16x8 af[2];
        #pragma unroll
        for (int rt = 0; rt < 2; rt++)
            af[rt] = *(const bf16x8*)&As[wid * 32 + rt * 16 + l15][lg * 8];
        #pragma unroll
        for (int ct = 0; ct < 16; ct++) {
            bf16x8 bfr = *(const bf16x8*)&Bs[ct * 16 + l15][lg * 8];
            #pragma unroll
            for (int rt = 0; rt < 2; rt++)
                acc[rt][ct] = __builtin_amdgcn_mfma_f32_16x16x32_bf16(
                    af[rt], bfr, acc[rt][ct], 0, 0, 0);
        }
    }

    // epilogue: D row=(lg*4+r) in 16-tile, col=l15
    #pragma unroll
    for (int ct = 0; ct < 16; ct++) {
        int col = ct * 16 + l15;
        float bb = bvec[col];
        #pragma unroll
        for (int rt = 0; rt < 2; rt++) {
            #pragma unroll
            for (int r = 0; r < 4; r++) {
                int row = row0 + wid * 32 + rt * 16 + lg * 4 + r;
                if (row < N_NODES)
                    outp[(size_t)row * 256 + col] = f2bf(acc[rt][ct][r] + bb);
            }
        }
    }
}

// ---------------- 2) CSR build by dst ----------------
__global__ __launch_bounds__(256) void count_deg(
    const int* __restrict__ dst, int* __restrict__ deg)
{
    int e = blockIdx.x * 256 + threadIdx.x;
    if (e < N_EDGES) atomicAdd(&deg[dst[e]], 1);
}

// block partial sums
__global__ __launch_bounds__(256) void deg_bsum(
    const int* __restrict__ deg, int* __restrict__ bsum)
{
    __shared__ int red[256];
    int t = threadIdx.x;
    int i = blockIdx.x * 256 + t;
    red[t] = (i < N_NODES) ? deg[i] : 0;
    __syncthreads();
    #pragma unroll
    for (int off = 128; off; off >>= 1) {
        if (t < off) red[t] += red[t + off];
        __syncthreads();
    }
    if (t == 0) bsum[blockIdx.x] = red[0];
}

// single small block: exclusive scan of 196 block sums
__global__ __launch_bounds__(256) void bsum_scan(
    const int* __restrict__ bsum, int* __restrict__ boff)
{
    __shared__ int s[256];
    int t = threadIdx.x;
    int v = (t < NB_SCAN) ? bsum[t] : 0;
    s[t] = v;
    __syncthreads();
    #pragma unroll
    for (int off = 1; off < 256; off <<= 1) {
        int x = (t >= off) ? s[t - off] : 0;
        __syncthreads();
        s[t] += x;
        __syncthreads();
    }
    if (t < NB_SCAN) boff[t] = s[t] - v;
}

// block-local scan + offset -> row_start
__global__ __launch_bounds__(256) void deg_scan_final(
    const int* __restrict__ deg, const int* __restrict__ boff,
    int* __restrict__ row_start)
{
    __shared__ int s[256];
    int t = threadIdx.x;
    int i = blockIdx.x * 256 + t;
    int v = (i < N_NODES) ? deg[i] : 0;
    s[t] = v;
    __syncthreads();
    #pragma unroll
    for (int off = 1; off < 256; off <<= 1) {
        int x = (t >= off) ? s[t - off] : 0;
        __syncthreads();
        s[t] += x;
        __syncthreads();
    }
    if (i < N_NODES) row_start[i] = boff[blockIdx.x] + s[t] - v;
    if (i == N_NODES) row_start[N_NODES] = N_EDGES;
}

__global__ __launch_bounds__(256) void scatter_edges(
    const int* __restrict__ src, const int* __restrict__ dst,
    const int* __restrict__ row_start, int* __restrict__ fill,
    int* __restrict__ eid_csr, int* __restrict__ src_csr,
    int* __restrict__ dstn_csr)
{
    int e = blockIdx.x * 256 + threadIdx.x;
    if (e >= N_EDGES) return;
    int d = dst[e];
    int pos = row_start[d] + atomicAdd(&fill[d], 1);
    eid_csr[pos] = e;
    src_csr[pos] = src[e];
    dstn_csr[pos] = d;
}

// ---------------- 3) fused per-node online-softmax aggregation ----------------
// one wave per node; lane owns dims 4*lane..4*lane+3; head = lane>>4
__global__ __launch_bounds__(256) void fused_node(
    const ushort* __restrict__ fsb, const ushort* __restrict__ fdb,
    const float* __restrict__ X, const float* __restrict__ bias,
    const int* __restrict__ row_start, const int* __restrict__ src_csr,
    const float* __restrict__ attn_w,
    float* __restrict__ logits_csr, float* __restrict__ m_buf,
    float* __restrict__ inv_buf, float* __restrict__ out)
{
    int n = blockIdx.x * 4 + (threadIdx.x >> 6);
    if (n >= N_NODES) return;
    int lane = threadIdx.x & 63;
    int h = lane >> 4;
    bool lead = (lane & 15) == 0;

    ushort4 fd4 = *(const ushort4*)&fdb[(size_t)n * 256 + lane * 4];
    float fdx = bf2f(fd4.x), fdy = bf2f(fd4.y), fdz = bf2f(fd4.z), fdw = bf2f(fd4.w);
    float4 w = *(const float4*)&attn_w[lane * 4];

    float m = -INFINITY, ssum = 0.f;
    float4 acc = make_float4(0.f, 0.f, 0.f, 0.f);

    int s0 = row_start[n], s1 = row_start[n + 1];
    for (int i = s0; i < s1; i += 4) {
        float4 u[4];
        float p[4];
        // 4 independent gathers + logit computations (MLP)
        #pragma unroll
        for (int j = 0; j < 4; j++) {
            int idx = (i + j < s1) ? (i + j) : (s1 - 1);
            int si = src_csr[idx];
            ushort4 u4 = *(const ushort4*)&fsb[(size_t)si * 256 + lane * 4];
            u[j].x = bf2f(u4.x); u[j].y = bf2f(u4.y);
            u[j].z = bf2f(u4.z); u[j].w = bf2f(u4.w);
            float t, pp = 0.f;
            t = u[j].x + fdx; t = t > 0.f ? t : NEG_SLOPE * t; pp += t * w.x;
            t = u[j].y + fdy; t = t > 0.f ? t : NEG_SLOPE * t; pp += t * w.y;
            t = u[j].z + fdz; t = t > 0.f ? t : NEG_SLOPE * t; pp += t * w.z;
            t = u[j].w + fdw; t = t > 0.f ? t : NEG_SLOPE * t; pp += t * w.w;
            #pragma unroll
            for (int off = 8; off; off >>= 1) pp += __shfl_xor(pp, off, 16);
            p[j] = pp;
        }
        // sequential online-softmax updates (actives are a prefix of the chunk)
        #pragma unroll
        for (int j = 0; j < 4; j++) {
            bool act = (i + j < s1);
            if (act && lead) logits_csr[(size_t)(i + j) * HEADS + h] = p[j];
            float pj = act ? p[j] : -INFINITY;
            float mn = fmaxf(m, pj);
            float sc = __expf(m - mn);    // first active: exp(-inf)=0
            float ex = __expf(pj - mn);   // inactive: exp(-inf)=0
            ssum = ssum * sc + ex;
            acc.x = acc.x * sc + u[j].x * ex;
            acc.y = acc.y * sc + u[j].y * ex;
            acc.z = acc.z * sc + u[j].z * ex;
            acc.w = acc.w * sc + u[j].w * ex;
            m = mn;
        }
    }
    float inv = ssum > 0.f ? 1.f / ssum : 0.f;
    if (lead) {
        m_buf[(size_t)n * HEADS + h] = m;
        inv_buf[(size_t)n * HEADS + h] = inv;
    }
    float4 xr = *(const float4*)&X[(size_t)n * NFEAT + lane * 4];
    float4 bb = *(const float4*)&bias[lane * 4];
    float4 o;
    o.x = acc.x * inv + xr.x + bb.x;
    o.y = acc.y * inv + xr.y + bb.y;
    o.z = acc.z * inv + xr.z + bb.z;
    o.w = acc.w * inv + xr.w + bb.w;
    *(float4*)&out[(size_t)n * NFEAT + lane * 4] = o;
}

// ---------------- 4) attention output (CSR order -> scatter by eid) ----------------
__global__ __launch_bounds__(256) void attn_norm(
    const int* __restrict__ eid_csr, const int* __restrict__ dstn_csr,
    const float* __restrict__ logits_csr,
    const float* __restrict__ m_buf, const float* __restrict__ inv_buf,
    float* __restrict__ attn_out)
{
    int i = blockIdx.x * 256 + threadIdx.x;
    if (i >= N_EDGES) return;
    int e = eid_csr[i];
    int d = dstn_csr[i];
    float4 lg = *(const float4*)&logits_csr[(size_t)i * 4];
    float4 mm = *(const float4*)&m_buf[(size_t)d * 4];
    float4 iv = *(const float4*)&inv_buf[(size_t)d * 4];
    float4 a;
    a.x = __expf(lg.x - mm.x) * iv.x;
    a.y = __expf(lg.y - mm.y) * iv.y;
    a.z = __expf(lg.z - mm.z) * iv.z;
    a.w = __expf(lg.w - mm.w) * iv.w;
    *(float4*)&attn_out[(size_t)e * 4] = a;
}

// ---------------- 5) BatchNorm ----------------
__global__ __launch_bounds__(256) void colstats(
    const float* __restrict__ outf,
    float* __restrict__ csum, float* __restrict__ csumsq)
{
    int c = threadIdx.x;
    float s0 = 0.f, s1 = 0.f;
    for (int r = blockIdx.x; r < N_NODES; r += gridDim.x) {
        float v = outf[(size_t)r * NFEAT + c];
        s0 += v; s1 += v * v;
    }
    atomicAdd(&csum[c], s0);
    atomicAdd(&csumsq[c], s1);
}

__global__ void finalize_stats(
    const float* __restrict__ csum, const float* __restrict__ csumsq,
    const float* __restrict__ gamma, const float* __restrict__ beta,
    float* __restrict__ scale, float* __restrict__ shift)
{
    int c = threadIdx.x;
    float mean = csum[c] * (1.0f / N_NODES);
    float var = csumsq[c] * (1.0f / N_NODES) - mean * mean;
    float sc = gamma[c] * rsqrtf(var + BN_EPS);
    scale[c] = sc;
    shift[c] = beta[c] - mean * sc;
}

__global__ __launch_bounds__(256) void bn_relu(
    float* __restrict__ outf,
    const float* __restrict__ scale, const float* __restrict__ shift)
{
    size_t i = (size_t)blockIdx.x * 256 + threadIdx.x;
    if (i >= (size_t)N_NODES * 64) return;
    int c4 = (int)(i & 63) * 4;
    float4 r = *(float4*)&outf[i * 4];
    float4 sc = *(const float4*)&scale[c4];
    float4 sh = *(const float4*)&shift[c4];
    float4 o;
    o.x = fmaxf(r.x * sc.x + sh.x, 0.f);
    o.y = fmaxf(r.y * sc.y + sh.y, 0.f);
    o.z = fmaxf(r.z * sc.z + sh.z, 0.f);
    o.w = fmaxf(r.w * sc.w + sh.w, 0.f);
    *(float4*)&outf[i * 4] = o;
}

extern "C" void kernel_launch(void* const* d_in, const int* in_sizes, int n_in,
                              void* d_out, int out_size, void* d_ws, size_t ws_size,
                              hipStream_t stream) {
    const float* X      = (const float*)d_in[0];
    const int*   src    = (const int*)d_in[1];
    const int*   dst    = (const int*)d_in[2];
    const float* Wsrc   = (const float*)d_in[3];
    const float* bsrc   = (const float*)d_in[4];
    const float* Wdst   = (const float*)d_in[5];
    const float* bdst   = (const float*)d_in[6];
    const float* attn_w = (const float*)d_in[7];
    const float* bias   = (const float*)d_in[8];
    const float* gamma  = (const float*)d_in[9];
    const float* beta   = (const float*)d_in[10];

    float* out      = (float*)d_out;                       // [N,256]
    float* attn_out = out + (size_t)N_NODES * NFEAT;       // [E,4]

    char* w = (char*)d_ws;
    ushort* fsb  = (ushort*)w;  w += (size_t)N_NODES * 256 * 2;
    ushort* fdb  = (ushort*)w;  w += (size_t)N_NODES * 256 * 2;
    ushort* WT   = (ushort*)w;  w += (size_t)512 * 256 * 2;
    float* logits_csr = (float*)w; w += (size_t)N_EDGES * HEADS * 4;
    float* m_buf   = (float*)w; w += (size_t)N_NODES * HEADS * 4;
    float* inv_buf = (float*)w; w += (size_t)N_NODES * HEADS * 4;
    float* csum    = (float*)w; w += 256 * 4;
    float* csumsq  = (float*)w; w += 256 * 4;
    float* scale   = (float*)w; w += 256 * 4;
    float* shift   = (float*)w; w += 256 * 4;
    int* deg       = (int*)w;   w += (size_t)N_NODES * 4;
    int* row_start = (int*)w;   w += (size_t)(N_NODES + 1) * 4;
    int* fill      = (int*)w;   w += (size_t)N_NODES * 4;
    int* eid_csr   = (int*)w;   w += (size_t)N_EDGES * 4;
    int* src_csr   = (int*)w;   w += (size_t)N_EDGES * 4;
    int* dstn_csr  = (int*)w;   w += (size_t)N_EDGES * 4;
    int* bsum      = (int*)w;   w += (size_t)NB_SCAN * 4;
    int* boff      = (int*)w;   w += (size_t)NB_SCAN * 4;

    hipMemsetAsync(deg,  0, N_NODES * sizeof(int), stream);
    hipMemsetAsync(fill, 0, N_NODES * sizeof(int), stream);
    hipMemsetAsync(csum, 0, 2 * 256 * sizeof(float), stream);

    prep_wt<<<512, 256, 0, stream>>>(Wsrc, Wdst, WT);
    proj_mfma<<<dim3((N_NODES + 127) / 128, 2), 256, 0, stream>>>(
        X, WT, bsrc, bdst, fsb, fdb);
    count_deg<<<(N_EDGES + 255) / 256, 256, 0, stream>>>(dst, deg);
    deg_bsum<<<NB_SCAN, 256, 0, stream>>>(deg, bsum);
    bsum_scan<<<1, 256, 0, stream>>>(bsum, boff);
    deg_scan_final<<<NB_SCAN, 256, 0, stream>>>(deg, boff, row_start);
    scatter_edges<<<(N_EDGES + 255) / 256, 256, 0, stream>>>(
        src, dst, row_start, fill, eid_csr, src_csr, dstn_csr);
    fused_node<<<(N_NODES + 3) / 4, 256, 0, stream>>>(
        fsb, fdb, X, bias, row_start, src_csr, attn_w,
        logits_csr, m_buf, inv_buf, out);
    attn_norm<<<(N_EDGES + 255) / 256, 256, 0, stream>>>(
        eid_csr, dstn_csr, logits_csr, m_buf, inv_buf, attn_out);
    colstats<<<512, 256, 0, stream>>>(out, csum, csumsq);
    finalize_stats<<<1, 256, 0, stream>>>(csum, csumsq, gamma, beta, scale, shift);
    bn_relu<<<(N_NODES * 64 + 255) / 256, 256, 0, stream>>>(out, scale, shift);
}

// Round 6
// 475.310 us; speedup vs baseline: 6.9266x; 1.0785x over previous
//
#include <hip/hip_runtime.h>
#include <hip/hip_bf16.h>
#include <cfloat>

// GATv2 layer pipeline (round 6):
//   0) cvt_x: X f32 -> Xb bf16 ; prep_wt: WT[n][k] = bf16(W[k][n]) (512x256)
//   1) proj_mfma: 64 rows x 128 cols per block; B panel LDS-resident (64KB,
//      XOR-swizzled, loaded once, single barrier); A streamed from global
//      directly into MFMA fragments (no K-loop barriers); XCD-aware work map.
//   2) CSR build: count_deg -> 3-kernel block scan -> scatter_edges
//   3) fused_node: wave/node online softmax, 8-edge unrolled gathers with
//      tree-merged softmax update
//   4) attn_norm; 5) colstats + finalize_stats + bn_relu

#define N_NODES 50000
#define N_EDGES 800000
#define NFEAT 256
#define HEADS 4
#define NEG_SLOPE 0.2f
#define BN_EPS 1e-5f
#define NB_SCAN 196        // ceil(50000/256)
#define NWG_PROJ 3128      // 782 row-tiles * 4 panels = 8 * 391
#define CPX_PROJ 391       // per-XCD chunk

typedef __attribute__((ext_vector_type(8))) short bf16x8;
typedef __attribute__((ext_vector_type(4))) float f32x4;
typedef __attribute__((ext_vector_type(8))) unsigned short u16x8;

__device__ __forceinline__ float bf2f(unsigned short u) {
    return __uint_as_float(((unsigned)u) << 16);
}
__device__ __forceinline__ unsigned short f2bf(float f) {
    unsigned u = __float_as_uint(f);
    unsigned r = u + 0x7FFFu + ((u >> 16) & 1u);
    return (unsigned short)(r >> 16);
}

// ---------------- 0) conversions ----------------
__global__ __launch_bounds__(256) void cvt_x(
    const float* __restrict__ X, ushort* __restrict__ Xb)
{
    size_t i = (size_t)blockIdx.x * 256 + threadIdx.x;   // float4 index
    if (i >= (size_t)N_NODES * 64) return;
    float4 v = *(const float4*)&X[i * 4];
    ushort4 o;
    o.x = f2bf(v.x); o.y = f2bf(v.y); o.z = f2bf(v.z); o.w = f2bf(v.w);
    *(ushort4*)&Xb[i * 4] = o;
}

__global__ __launch_bounds__(256) void prep_wt(
    const float* __restrict__ Wsrc, const float* __restrict__ Wdst,
    ushort* __restrict__ WT)
{
    int n = blockIdx.x;
    int k = threadIdx.x;
    const float* W = (n < 256) ? Wsrc : Wdst;
    int nc = n & 255;
    WT[(size_t)n * 256 + k] = f2bf(W[(size_t)k * 256 + nc]);
}

// ---------------- 1) MFMA projection GEMM ----------------
// block = 4 waves; work unit = 64 rows x 128 concat-cols; K=256.
// Bs: [128 n][256 k] bf16, 64KB, XOR-swizzled 16B slots: byte ^= (n&7)<<4.
__global__ __launch_bounds__(256) void proj_mfma(
    const ushort* __restrict__ Xb, const ushort* __restrict__ WT,
    const float* __restrict__ bsrc, const float* __restrict__ bdst,
    ushort* __restrict__ fsb, ushort* __restrict__ fdb)
{
    __shared__ ushort Bs[128 * 256];   // exactly 64 KB

    const int tid = threadIdx.x;
    // bijective XCD-aware work map (panel-fastest work order)
    const int bid = blockIdx.x;
    const int work = (bid & 7) * CPX_PROJ + (bid >> 3);
    const int panel = work & 3;            // 0..3 over concat 512 cols
    const int row0 = (work >> 2) * 64;
    const int ncol0 = panel * 128;         // concat col base

    // stage B panel once: 128 rows (cols of W) x 256 k, swizzled
    {
        int r = tid >> 1;                  // 0..127
        int half = tid & 1;                // 256B half of the 512B row
        const ushort* p = &WT[(size_t)(ncol0 + r) * 256 + half * 128];
        int rbase = r * 512;
        int sw = (r & 7) << 4;
        #pragma unroll
        for (int j = 0; j < 16; j++) {
            int byte = (rbase + (half * 128 + j * 8) * 2) ^ sw;
            *(u16x8*)((char*)Bs + byte) = *(const u16x8*)(p + j * 8);
        }
    }
    __syncthreads();

    const int wid = tid >> 6, lane = tid & 63;
    const int l15 = lane & 15, lg = lane >> 4;

    const int arow = row0 + wid * 16 + l15;
    const bool aok = arow < N_NODES;
    const ushort* aptr = &Xb[(size_t)arow * 256];

    f32x4 acc[8] = {};

    #pragma unroll
    for (int ks = 0; ks < 8; ks++) {
        const int k0 = ks * 32;
        bf16x8 af = {};
        if (aok) af = *(const bf16x8*)(aptr + k0 + lg * 8);
        #pragma unroll
        for (int ct = 0; ct < 8; ct++) {
            int brow = ct * 16 + l15;
            int byte = (brow * 512 + (k0 + lg * 8) * 2) ^ ((brow & 7) << 4);
            bf16x8 bfr = *(const bf16x8*)((const char*)Bs + byte);
            acc[ct] = __builtin_amdgcn_mfma_f32_16x16x32_bf16(af, bfr, acc[ct], 0, 0, 0);
        }
    }

    // epilogue: D row = lg*4 + r within 16-tile, col = l15
    const float* bvec = (panel < 2) ? bsrc : bdst;
    ushort* outp = (panel < 2) ? fsb : fdb;
    const int colbase = (panel & 1) * 128;
    #pragma unroll
    for (int ct = 0; ct < 8; ct++) {
        int col = colbase + ct * 16 + l15;
        float bb = bvec[col];
        #pragma unroll
        for (int r = 0; r < 4; r++) {
            int row = row0 + wid * 16 + lg * 4 + r;
            if (row < N_NODES)
                outp[(size_t)row * 256 + col] = f2bf(acc[ct][r] + bb);
        }
    }
}

// ---------------- 2) CSR build by dst ----------------
__global__ __launch_bounds__(256) void count_deg(
    const int* __restrict__ dst, int* __restrict__ deg)
{
    int e = blockIdx.x * 256 + threadIdx.x;
    if (e < N_EDGES) atomicAdd(&deg[dst[e]], 1);
}

__global__ __launch_bounds__(256) void deg_bsum(
    const int* __restrict__ deg, int* __restrict__ bsum)
{
    __shared__ int red[256];
    int t = threadIdx.x;
    int i = blockIdx.x * 256 + t;
    red[t] = (i < N_NODES) ? deg[i] : 0;
    __syncthreads();
    #pragma unroll
    for (int off = 128; off; off >>= 1) {
        if (t < off) red[t] += red[t + off];
        __syncthreads();
    }
    if (t == 0) bsum[blockIdx.x] = red[0];
}

__global__ __launch_bounds__(256) void bsum_scan(
    const int* __restrict__ bsum, int* __restrict__ boff)
{
    __shared__ int s[256];
    int t = threadIdx.x;
    int v = (t < NB_SCAN) ? bsum[t] : 0;
    s[t] = v;
    __syncthreads();
    #pragma unroll
    for (int off = 1; off < 256; off <<= 1) {
        int x = (t >= off) ? s[t - off] : 0;
        __syncthreads();
        s[t] += x;
        __syncthreads();
    }
    if (t < NB_SCAN) boff[t] = s[t] - v;
}

__global__ __launch_bounds__(256) void deg_scan_final(
    const int* __restrict__ deg, const int* __restrict__ boff,
    int* __restrict__ row_start)
{
    __shared__ int s[256];
    int t = threadIdx.x;
    int i = blockIdx.x * 256 + t;
    int v = (i < N_NODES) ? deg[i] : 0;
    s[t] = v;
    __syncthreads();
    #pragma unroll
    for (int off = 1; off < 256; off <<= 1) {
        int x = (t >= off) ? s[t - off] : 0;
        __syncthreads();
        s[t] += x;
        __syncthreads();
    }
    if (i < N_NODES) row_start[i] = boff[blockIdx.x] + s[t] - v;
    if (i == N_NODES) row_start[N_NODES] = N_EDGES;
}

__global__ __launch_bounds__(256) void scatter_edges(
    const int* __restrict__ src, const int* __restrict__ dst,
    const int* __restrict__ row_start, int* __restrict__ fill,
    int* __restrict__ eid_csr, int* __restrict__ src_csr,
    int* __restrict__ dstn_csr)
{
    int e = blockIdx.x * 256 + threadIdx.x;
    if (e >= N_EDGES) return;
    int d = dst[e];
    int pos = row_start[d] + atomicAdd(&fill[d], 1);
    eid_csr[pos] = e;
    src_csr[pos] = src[e];
    dstn_csr[pos] = d;
}

// ---------------- 3) fused per-node online-softmax aggregation ----------------
// one wave per node; lane owns dims 4*lane..4*lane+3; head = lane>>4
__global__ __launch_bounds__(256) void fused_node(
    const ushort* __restrict__ fsb, const ushort* __restrict__ fdb,
    const float* __restrict__ X, const float* __restrict__ bias,
    const int* __restrict__ row_start, const int* __restrict__ src_csr,
    const float* __restrict__ attn_w,
    float* __restrict__ logits_csr, float* __restrict__ m_buf,
    float* __restrict__ inv_buf, float* __restrict__ out)
{
    int n = blockIdx.x * 4 + (threadIdx.x >> 6);
    if (n >= N_NODES) return;
    int lane = threadIdx.x & 63;
    int h = lane >> 4;
    bool lead = (lane & 15) == 0;

    ushort4 fd4 = *(const ushort4*)&fdb[(size_t)n * 256 + lane * 4];
    float fdx = bf2f(fd4.x), fdy = bf2f(fd4.y), fdz = bf2f(fd4.z), fdw = bf2f(fd4.w);
    float4 w = *(const float4*)&attn_w[lane * 4];

    float m = -INFINITY, ssum = 0.f;
    float4 acc = make_float4(0.f, 0.f, 0.f, 0.f);

    int s0 = row_start[n], s1 = row_start[n + 1];
    for (int i = s0; i < s1; i += 8) {
        float4 u[8];
        float p[8];
        // 8 independent gathers + logit computations (MLP)
        #pragma unroll
        for (int j = 0; j < 8; j++) {
            int idx = (i + j < s1) ? (i + j) : (s1 - 1);
            int si = src_csr[idx];
            ushort4 u4 = *(const ushort4*)&fsb[(size_t)si * 256 + lane * 4];
            u[j].x = bf2f(u4.x); u[j].y = bf2f(u4.y);
            u[j].z = bf2f(u4.z); u[j].w = bf2f(u4.w);
            float t, pp = 0.f;
            t = u[j].x + fdx; t = t > 0.f ? t : NEG_SLOPE * t; pp += t * w.x;
            t = u[j].y + fdy; t = t > 0.f ? t : NEG_SLOPE * t; pp += t * w.y;
            t = u[j].z + fdz; t = t > 0.f ? t : NEG_SLOPE * t; pp += t * w.z;
            t = u[j].w + fdw; t = t > 0.f ? t : NEG_SLOPE * t; pp += t * w.w;
            #pragma unroll
            for (int off = 8; off; off >>= 1) pp += __shfl_xor(pp, off, 16);
            p[j] = pp;
        }
        // store logits; mask inactive to -inf
        #pragma unroll
        for (int j = 0; j < 8; j++) {
            bool act = (i + j < s1);
            if (act && lead) logits_csr[(size_t)(i + j) * HEADS + h] = p[j];
            if (!act) p[j] = -INFINITY;
        }
        // tree-merged online softmax update (single rescale per chunk)
        float cm = fmaxf(fmaxf(fmaxf(p[0], p[1]), fmaxf(p[2], p[3])),
                         fmaxf(fmaxf(p[4], p[5]), fmaxf(p[6], p[7])));
        float mn = fmaxf(m, cm);
        float sc = __expf(m - mn);     // first chunk: exp(-inf - finite) = 0
        float e[8];
        #pragma unroll
        for (int j = 0; j < 8; j++) e[j] = __expf(p[j] - mn);
        float es = ((e[0] + e[1]) + (e[2] + e[3])) + ((e[4] + e[5]) + (e[6] + e[7]));
        ssum = ssum * sc + es;
        float ax = acc.x * sc, ay = acc.y * sc, az = acc.z * sc, aw = acc.w * sc;
        #pragma unroll
        for (int j = 0; j < 8; j++) {
            ax += u[j].x * e[j];
            ay += u[j].y * e[j];
            az += u[j].z * e[j];
            aw += u[j].w * e[j];
        }
        acc.x = ax; acc.y = ay; acc.z = az; acc.w = aw;
        m = mn;
    }
    float inv = ssum > 0.f ? 1.f / ssum : 0.f;
    if (lead) {
        m_buf[(size_t)n * HEADS + h] = m;
        inv_buf[(size_t)n * HEADS + h] = inv;
    }
    float4 xr = *(const float4*)&X[(size_t)n * NFEAT + lane * 4];
    float4 bb = *(const float4*)&bias[lane * 4];
    float4 o;
    o.x = acc.x * inv + xr.x + bb.x;
    o.y = acc.y * inv + xr.y + bb.y;
    o.z = acc.z * inv + xr.z + bb.z;
    o.w = acc.w * inv + xr.w + bb.w;
    *(float4*)&out[(size_t)n * NFEAT + lane * 4] = o;
}

// ---------------- 4) attention output (CSR order -> scatter by eid) ----------------
__global__ __launch_bounds__(256) void attn_norm(
    const int* __restrict__ eid_csr, const int* __restrict__ dstn_csr,
    const float* __restrict__ logits_csr,
    const float* __restrict__ m_buf, const float* __restrict__ inv_buf,
    float* __restrict__ attn_out)
{
    int i = blockIdx.x * 256 + threadIdx.x;
    if (i >= N_EDGES) return;
    int e = eid_csr[i];
    int d = dstn_csr[i];
    float4 lg = *(const float4*)&logits_csr[(size_t)i * 4];
    float4 mm = *(const float4*)&m_buf[(size_t)d * 4];
    float4 iv = *(const float4*)&inv_buf[(size_t)d * 4];
    float4 a;
    a.x = __expf(lg.x - mm.x) * iv.x;
    a.y = __expf(lg.y - mm.y) * iv.y;
    a.z = __expf(lg.z - mm.z) * iv.z;
    a.w = __expf(lg.w - mm.w) * iv.w;
    *(float4*)&attn_out[(size_t)e * 4] = a;
}

// ---------------- 5) BatchNorm ----------------
__global__ __launch_bounds__(256) void colstats(
    const float* __restrict__ outf,
    float* __restrict__ csum, float* __restrict__ csumsq)
{
    int c = threadIdx.x;
    float s0 = 0.f, s1 = 0.f;
    for (int r = blockIdx.x; r < N_NODES; r += gridDim.x) {
        float v = outf[(size_t)r * NFEAT + c];
        s0 += v; s1 += v * v;
    }
    atomicAdd(&csum[c], s0);
    atomicAdd(&csumsq[c], s1);
}

__global__ void finalize_stats(
    const float* __restrict__ csum, const float* __restrict__ csumsq,
    const float* __restrict__ gamma, const float* __restrict__ beta,
    float* __restrict__ scale, float* __restrict__ shift)
{
    int c = threadIdx.x;
    float mean = csum[c] * (1.0f / N_NODES);
    float var = csumsq[c] * (1.0f / N_NODES) - mean * mean;
    float sc = gamma[c] * rsqrtf(var + BN_EPS);
    scale[c] = sc;
    shift[c] = beta[c] - mean * sc;
}

__global__ __launch_bounds__(256) void bn_relu(
    float* __restrict__ outf,
    const float* __restrict__ scale, const float* __restrict__ shift)
{
    size_t i = (size_t)blockIdx.x * 256 + threadIdx.x;
    if (i >= (size_t)N_NODES * 64) return;
    int c4 = (int)(i & 63) * 4;
    float4 r = *(float4*)&outf[i * 4];
    float4 sc = *(const float4*)&scale[c4];
    float4 sh = *(const float4*)&shift[c4];
    float4 o;
    o.x = fmaxf(r.x * sc.x + sh.x, 0.f);
    o.y = fmaxf(r.y * sc.y + sh.y, 0.f);
    o.z = fmaxf(r.z * sc.z + sh.z, 0.f);
    o.w = fmaxf(r.w * sc.w + sh.w, 0.f);
    *(float4*)&outf[i * 4] = o;
}

extern "C" void kernel_launch(void* const* d_in, const int* in_sizes, int n_in,
                              void* d_out, int out_size, void* d_ws, size_t ws_size,
                              hipStream_t stream) {
    const float* X      = (const float*)d_in[0];
    const int*   src    = (const int*)d_in[1];
    const int*   dst    = (const int*)d_in[2];
    const float* Wsrc   = (const float*)d_in[3];
    const float* bsrc   = (const float*)d_in[4];
    const float* Wdst   = (const float*)d_in[5];
    const float* bdst   = (const float*)d_in[6];
    const float* attn_w = (const float*)d_in[7];
    const float* bias   = (const float*)d_in[8];
    const float* gamma  = (const float*)d_in[9];
    const float* beta   = (const float*)d_in[10];

    float* out      = (float*)d_out;                       // [N,256]
    float* attn_out = out + (size_t)N_NODES * NFEAT;       // [E,4]

    char* w = (char*)d_ws;
    ushort* Xb   = (ushort*)w;  w += (size_t)N_NODES * 256 * 2;
    ushort* fsb  = (ushort*)w;  w += (size_t)N_NODES * 256 * 2;
    ushort* fdb  = (ushort*)w;  w += (size_t)N_NODES * 256 * 2;
    ushort* WT   = (ushort*)w;  w += (size_t)512 * 256 * 2;
    float* logits_csr = (float*)w; w += (size_t)N_EDGES * HEADS * 4;
    float* m_buf   = (float*)w; w += (size_t)N_NODES * HEADS * 4;
    float* inv_buf = (float*)w; w += (size_t)N_NODES * HEADS * 4;
    float* csum    = (float*)w; w += 256 * 4;
    float* csumsq  = (float*)w; w += 256 * 4;
    float* scale   = (float*)w; w += 256 * 4;
    float* shift   = (float*)w; w += 256 * 4;
    int* deg       = (int*)w;   w += (size_t)N_NODES * 4;
    int* row_start = (int*)w;   w += (size_t)(N_NODES + 1) * 4;
    int* fill      = (int*)w;   w += (size_t)N_NODES * 4;
    int* eid_csr   = (int*)w;   w += (size_t)N_EDGES * 4;
    int* src_csr   = (int*)w;   w += (size_t)N_EDGES * 4;
    int* dstn_csr  = (int*)w;   w += (size_t)N_EDGES * 4;
    int* bsum      = (int*)w;   w += (size_t)NB_SCAN * 4;
    int* boff      = (int*)w;   w += (size_t)NB_SCAN * 4;

    hipMemsetAsync(deg,  0, N_NODES * sizeof(int), stream);
    hipMemsetAsync(fill, 0, N_NODES * sizeof(int), stream);
    hipMemsetAsync(csum, 0, 2 * 256 * sizeof(float), stream);

    cvt_x<<<(N_NODES * 64 + 255) / 256, 256, 0, stream>>>(X, Xb);
    prep_wt<<<512, 256, 0, stream>>>(Wsrc, Wdst, WT);
    proj_mfma<<<NWG_PROJ, 256, 0, stream>>>(Xb, WT, bsrc, bdst, fsb, fdb);
    count_deg<<<(N_EDGES + 255) / 256, 256, 0, stream>>>(dst, deg);
    deg_bsum<<<NB_SCAN, 256, 0, stream>>>(deg, bsum);
    bsum_scan<<<1, 256, 0, stream>>>(bsum, boff);
    deg_scan_final<<<NB_SCAN, 256, 0, stream>>>(deg, boff, row_start);
    scatter_edges<<<(N_EDGES + 255) / 256, 256, 0, stream>>>(
        src, dst, row_start, fill, eid_csr, src_csr, dstn_csr);
    fused_node<<<(N_NODES + 3) / 4, 256, 0, stream>>>(
        fsb, fdb, X, bias, row_start, src_csr, attn_w,
        logits_csr, m_buf, inv_buf, out);
    attn_norm<<<(N_EDGES + 255) / 256, 256, 0, stream>>>(
        eid_csr, dstn_csr, logits_csr, m_buf, inv_buf, attn_out);
    colstats<<<512, 256, 0, stream>>>(out, csum, csumsq);
    finalize_stats<<<1, 256, 0, stream>>>(csum, csumsq, gamma, beta, scale, shift);
    bn_relu<<<(N_NODES * 64 + 255) / 256, 256, 0, stream>>>(out, scale, shift);
}